// Round 9
// baseline (297.403 us; speedup 1.0000x reference)
//
#include <hip/hip_runtime.h>
#include <math.h>

#define Bsz 512
#define NA  128
#define NL  512
#define Dd  128
#define KA  16
#define KL  16

// ---------------------------------------------------------------------------
// Kernel A: per-batch index selection (one block per batch) — proven R5-R7.
// ---------------------------------------------------------------------------
__global__ __launch_bounds__(256) void idx_kernel(
    const float* __restrict__ spike, const unsigned char* __restrict__ avalid,
    const float* __restrict__ xc, const float* __restrict__ lc,
    const unsigned char* __restrict__ lvalid,
    int* __restrict__ aidx, int* __restrict__ lidx) {
  const int b = blockIdx.x;
  const int tid = threadIdx.x;

  __shared__ float s_ax[KA], s_ay[KA];
  __shared__ int   s_ai[KA];
  __shared__ float s_ld[NL];
  __shared__ float s_rv[4];
  __shared__ int   s_ri[4];
  __shared__ int   s_flag;

  if (tid == 0) s_flag = 0;
  __syncthreads();
  {
    int any = 0;
    for (int i = tid; i < 4096; i += 256)
      if ((i & 3) && avalid[i]) any = 1;
    if (any) atomicOr(&s_flag, 1);
  }
  __syncthreads();
  const int isbyte = s_flag;

#define VALID_AT(P, I) (isbyte ? (int)(P)[I] : ((const int*)(P))[I])

  if (tid < 64) {
    float v0 = VALID_AT(avalid, b * NA + tid)      ? spike[b * NA + tid]      : -INFINITY;
    float v1 = VALID_AT(avalid, b * NA + tid + 64) ? spike[b * NA + tid + 64] : -INFINITY;
    for (int it = 0; it < KA; ++it) {
      float bv = v0; int bi = tid;
      if (v1 > bv) { bv = v1; bi = tid + 64; }
      for (int off = 32; off; off >>= 1) {
        float ov = __shfl_xor(bv, off);
        int   oi = __shfl_xor(bi, off);
        if (ov > bv || (ov == bv && oi < bi)) { bv = ov; bi = oi; }
      }
      if (bi == tid)      v0 = -INFINITY;
      if (bi == tid + 64) v1 = -INFINITY;
      if (tid == 0) s_ai[it] = bi;
    }
  }
  __syncthreads();
  if (tid < KA) {
    int a = s_ai[tid];
    aidx[b * KA + tid] = a;
    s_ax[tid] = xc[(b * NA + a) * 2 + 0];
    s_ay[tid] = xc[(b * NA + a) * 2 + 1];
  }
  __syncthreads();

  for (int l = tid; l < NL; l += 256) {
    float lx = lc[(b * NL + l) * 2 + 0];
    float ly = lc[(b * NL + l) * 2 + 1];
    float best = INFINITY;
#pragma unroll
    for (int a = 0; a < KA; ++a) {
      float dx = s_ax[a] - lx, dy = s_ay[a] - ly;
      float d2 = __fadd_rn(__fmul_rn(dx, dx), __fmul_rn(dy, dy));
      best = fminf(best, d2);
    }
    best = sqrtf(best);
    s_ld[l] = VALID_AT(lvalid, b * NL + l) ? best : INFINITY;
  }
  __syncthreads();

  const int wid = tid >> 6, lane = tid & 63;
  for (int it = 0; it < KL; ++it) {
    float bv = s_ld[tid]; int bi = tid;
    float v2 = s_ld[tid + 256];
    if (v2 < bv) { bv = v2; bi = tid + 256; }
    for (int off = 32; off; off >>= 1) {
      float ov = __shfl_xor(bv, off);
      int   oi = __shfl_xor(bi, off);
      if (ov < bv || (ov == bv && oi < bi)) { bv = ov; bi = oi; }
    }
    if (lane == 0) { s_rv[wid] = bv; s_ri[wid] = bi; }
    __syncthreads();
    if (tid == 0) {
      float fbv = s_rv[0]; int fbi = s_ri[0];
      for (int w = 1; w < 4; ++w)
        if (s_rv[w] < fbv || (s_rv[w] == fbv && s_ri[w] < fbi)) { fbv = s_rv[w]; fbi = s_ri[w]; }
      lidx[b * KL + it] = fbi;
      s_ld[fbi] = INFINITY;
    }
    __syncthreads();
  }
#undef VALID_AT
}

// ---------------------------------------------------------------------------
// Kernel B (mlp3, k-coverage FIXED): one WAVE per batch (64 threads).
// 8x8 register-tile outer-product:
//   lane = (r = tid>>4, c = tid&15)
//   rows  {r + 4*i}, i<8; cols {4c..4c+3} and {64+4c..64+4c+3} (two b128s)
// Weights staged to LDS in EIGHT 16-k chunks (8 KB), double-buffered,
// reg-prefetch of chunk q+1 issued before FMA(q). k covers 0..127.
// ---------------------------------------------------------------------------

__device__ __forceinline__ float gelu1(float t) {
  return 0.5f * t * (1.0f + erff(t * 0.70710678118654752f));
}

#define FMA8(XS, KK)                                                  \
  acc[i][0].x = fmaf((XS), wv0[KK].x, acc[i][0].x);                   \
  acc[i][0].y = fmaf((XS), wv0[KK].y, acc[i][0].y);                   \
  acc[i][0].z = fmaf((XS), wv0[KK].z, acc[i][0].z);                   \
  acc[i][0].w = fmaf((XS), wv0[KK].w, acc[i][0].w);                   \
  acc[i][1].x = fmaf((XS), wv1[KK].x, acc[i][1].x);                   \
  acc[i][1].y = fmaf((XS), wv1[KK].y, acc[i][1].y);                   \
  acc[i][1].z = fmaf((XS), wv1[KK].z, acc[i][1].z);                   \
  acc[i][1].w = fmaf((XS), wv1[KK].w, acc[i][1].w);

// One matvec: acc = SRC(32x128) @ WM(128x128) + bias.
// 8 chunks of 16 k-rows; prefetches chunk q+1 (or GNEXT chunk 0 at q=7).
#define MATVEC3(SRC, WM, GNEXT, BV)                                           \
  {                                                                           \
    float4 bv0 = *(const float4*)((BV) + 4 * c);                              \
    float4 bv1 = *(const float4*)((BV) + 64 + 4 * c);                         \
    _Pragma("unroll")                                                         \
    for (int i = 0; i < 8; ++i) { acc[i][0] = bv0; acc[i][1] = bv1; }         \
    _Pragma("unroll 1")                                                       \
    for (int q = 0; q < 8; ++q) {                                             \
      const float4* gn = (q < 7) ? (const float4*)((WM) + (q + 1) * 2048)     \
                                 : (const float4*)(GNEXT);                    \
      float4 pf0, pf1, pf2, pf3, pf4, pf5, pf6, pf7;                          \
      if (gn) {                                                               \
        pf0 = gn[0 * 64 + tid]; pf1 = gn[1 * 64 + tid];                       \
        pf2 = gn[2 * 64 + tid]; pf3 = gn[3 * 64 + tid];                       \
        pf4 = gn[4 * 64 + tid]; pf5 = gn[5 * 64 + tid];                       \
        pf6 = gn[6 * 64 + tid]; pf7 = gn[7 * 64 + tid];                       \
      }                                                                       \
      const float* wq = s_w + cur * 2048;                                     \
      _Pragma("unroll")                                                       \
      for (int ch = 0; ch < 4; ++ch) {                                        \
        float4 wv0[4], wv1[4];                                                \
        _Pragma("unroll")                                                     \
        for (int kk = 0; kk < 4; ++kk) {                                      \
          wv0[kk] = *(const float4*)(wq + (ch * 4 + kk) * 128 + 4 * c);       \
          wv1[kk] = *(const float4*)(wq + (ch * 4 + kk) * 128 + 64 + 4 * c);  \
        }                                                                     \
        _Pragma("unroll")                                                     \
        for (int i = 0; i < 8; ++i) {                                         \
          float4 xv = *(const float4*)((SRC) + (r + 4 * i) * 132 + q * 16 + ch * 4); \
          FMA8(xv.x, 0) FMA8(xv.y, 1) FMA8(xv.z, 2) FMA8(xv.w, 3)             \
        }                                                                     \
      }                                                                       \
      if (gn) {                                                               \
        float4* wd = (float4*)(s_w + (cur ^ 1) * 2048);                       \
        wd[0 * 64 + tid] = pf0; wd[1 * 64 + tid] = pf1;                       \
        wd[2 * 64 + tid] = pf2; wd[3 * 64 + tid] = pf3;                       \
        wd[4 * 64 + tid] = pf4; wd[5 * 64 + tid] = pf5;                       \
        wd[6 * 64 + tid] = pf6; wd[7 * 64 + tid] = pf7;                       \
        cur ^= 1;                                                             \
      }                                                                       \
      __syncthreads();  /* 1 wave: ~lgkmcnt(0)+trivial barrier; orders dbuf */ \
    }                                                                         \
  }

__global__ __launch_bounds__(64) void mlp3_kernel(
    const float* __restrict__ actor_feat, const float* __restrict__ lane_feat,
    const int* __restrict__ aidx, const int* __restrict__ lidx,
    const float* __restrict__ W0a, const float* __restrict__ b0a,
    const float* __restrict__ W0b, const float* __restrict__ b0b,
    const float* __restrict__ W1a, const float* __restrict__ b1a,
    const float* __restrict__ W1b, const float* __restrict__ b1b,
    const float* __restrict__ gamma, const float* __restrict__ beta,
    float* __restrict__ out0, float* __restrict__ out1) {
  __shared__ float s_x[32 * 132];   // x, then LN0 output (residual base)
  __shared__ float s_u[32 * 132];   // gelu outputs
  __shared__ float s_w[2 * 2048];   // double-buffered 16k x 128j weight chunk
  __shared__ int   s_src[32];

  const int tid = threadIdx.x;       // = lane (1 wave)
  const int b = blockIdx.x;
  const int c = tid & 15, r = tid >> 4;

  if (tid < 32)
    s_src[tid] = (tid < 16) ? aidx[b * KA + tid] : lidx[b * KL + tid - 16];
  __syncthreads();

  // ---- gather 32 rows (coalesced float4) into padded [32][132] ----
#pragma unroll
  for (int t = 0; t < 16; ++t) {
    int q = tid + 64 * t;
    int row = q >> 5, c4 = q & 31;
    int s = s_src[row];
    const float* src = (row < 16)
        ? actor_feat + ((size_t)b * NA + s) * Dd
        : lane_feat  + ((size_t)b * NL + s) * Dd;
    *(float4*)&s_x[row * 132 + c4 * 4] = ((const float4*)src)[c4];
  }

  // ---- stage W0a chunk 0 ----
  {
    const float4* g = (const float4*)W0a;
    float4* wd = (float4*)s_w;
#pragma unroll
    for (int t = 0; t < 8; ++t) wd[t * 64 + tid] = g[t * 64 + tid];
  }
  __syncthreads();

  const float4 g40 = *(const float4*)(gamma + 4 * c);
  const float4 g41 = *(const float4*)(gamma + 64 + 4 * c);
  const float4 be0 = *(const float4*)(beta + 4 * c);
  const float4 be1 = *(const float4*)(beta + 64 + 4 * c);

  int cur = 0;
  float4 acc[8][2];

  // ================= layer 0 =================
  MATVEC3(s_x, W0a, W0b, b0a);
  // GELU -> s_u
#pragma unroll
  for (int i = 0; i < 8; ++i) {
    float4 o0, o1;
    o0.x = gelu1(acc[i][0].x); o0.y = gelu1(acc[i][0].y);
    o0.z = gelu1(acc[i][0].z); o0.w = gelu1(acc[i][0].w);
    o1.x = gelu1(acc[i][1].x); o1.y = gelu1(acc[i][1].y);
    o1.z = gelu1(acc[i][1].z); o1.w = gelu1(acc[i][1].w);
    *(float4*)&s_u[(r + 4 * i) * 132 + 4 * c] = o0;
    *(float4*)&s_u[(r + 4 * i) * 132 + 64 + 4 * c] = o1;
  }
  __syncthreads();

  MATVEC3(s_u, W0b, W1a, b0b);
  // residual + LN -> s_x (layer-1 input and residual base)
#pragma unroll
  for (int i = 0; i < 8; ++i) {
    const int row = r + 4 * i;
    float4 rx0 = *(const float4*)&s_x[row * 132 + 4 * c];
    float4 rx1 = *(const float4*)&s_x[row * 132 + 64 + 4 * c];
    float4 h0, h1;
    h0.x = rx0.x + acc[i][0].x; h0.y = rx0.y + acc[i][0].y;
    h0.z = rx0.z + acc[i][0].z; h0.w = rx0.w + acc[i][0].w;
    h1.x = rx1.x + acc[i][1].x; h1.y = rx1.y + acc[i][1].y;
    h1.z = rx1.z + acc[i][1].z; h1.w = rx1.w + acc[i][1].w;
    float sum = h0.x + h0.y + h0.z + h0.w + h1.x + h1.y + h1.z + h1.w;
    for (int off = 8; off; off >>= 1) sum += __shfl_xor(sum, off);
    float mean = sum * (1.0f / 128.0f);
    float4 d0, d1;
    d0.x = h0.x - mean; d0.y = h0.y - mean; d0.z = h0.z - mean; d0.w = h0.w - mean;
    d1.x = h1.x - mean; d1.y = h1.y - mean; d1.z = h1.z - mean; d1.w = h1.w - mean;
    float sq = d0.x*d0.x + d0.y*d0.y + d0.z*d0.z + d0.w*d0.w
             + d1.x*d1.x + d1.y*d1.y + d1.z*d1.z + d1.w*d1.w;
    for (int off = 8; off; off >>= 1) sq += __shfl_xor(sq, off);
    float inv = 1.0f / sqrtf(sq * (1.0f / 128.0f) + 1e-5f);
    float4 v0, v1;
    v0.x = d0.x*inv*g40.x + be0.x; v0.y = d0.y*inv*g40.y + be0.y;
    v0.z = d0.z*inv*g40.z + be0.z; v0.w = d0.w*inv*g40.w + be0.w;
    v1.x = d1.x*inv*g41.x + be1.x; v1.y = d1.y*inv*g41.y + be1.y;
    v1.z = d1.z*inv*g41.z + be1.z; v1.w = d1.w*inv*g41.w + be1.w;
    *(float4*)&s_x[row * 132 + 4 * c] = v0;
    *(float4*)&s_x[row * 132 + 64 + 4 * c] = v1;
  }
  __syncthreads();

  // ================= layer 1 =================
  MATVEC3(s_x, W1a, W1b, b1a);
#pragma unroll
  for (int i = 0; i < 8; ++i) {
    float4 o0, o1;
    o0.x = gelu1(acc[i][0].x); o0.y = gelu1(acc[i][0].y);
    o0.z = gelu1(acc[i][0].z); o0.w = gelu1(acc[i][0].w);
    o1.x = gelu1(acc[i][1].x); o1.y = gelu1(acc[i][1].y);
    o1.z = gelu1(acc[i][1].z); o1.w = gelu1(acc[i][1].w);
    *(float4*)&s_u[(r + 4 * i) * 132 + 4 * c] = o0;
    *(float4*)&s_u[(r + 4 * i) * 132 + 64 + 4 * c] = o1;
  }
  __syncthreads();

  MATVEC3(s_u, W1b, (const float*)0, b1b);
  // residual + LN -> scatter to global
#pragma unroll
  for (int i = 0; i < 8; ++i) {
    const int row = r + 4 * i;
    float4 rx0 = *(const float4*)&s_x[row * 132 + 4 * c];
    float4 rx1 = *(const float4*)&s_x[row * 132 + 64 + 4 * c];
    float4 h0, h1;
    h0.x = rx0.x + acc[i][0].x; h0.y = rx0.y + acc[i][0].y;
    h0.z = rx0.z + acc[i][0].z; h0.w = rx0.w + acc[i][0].w;
    h1.x = rx1.x + acc[i][1].x; h1.y = rx1.y + acc[i][1].y;
    h1.z = rx1.z + acc[i][1].z; h1.w = rx1.w + acc[i][1].w;
    float sum = h0.x + h0.y + h0.z + h0.w + h1.x + h1.y + h1.z + h1.w;
    for (int off = 8; off; off >>= 1) sum += __shfl_xor(sum, off);
    float mean = sum * (1.0f / 128.0f);
    float4 d0, d1;
    d0.x = h0.x - mean; d0.y = h0.y - mean; d0.z = h0.z - mean; d0.w = h0.w - mean;
    d1.x = h1.x - mean; d1.y = h1.y - mean; d1.z = h1.z - mean; d1.w = h1.w - mean;
    float sq = d0.x*d0.x + d0.y*d0.y + d0.z*d0.z + d0.w*d0.w
             + d1.x*d1.x + d1.y*d1.y + d1.z*d1.z + d1.w*d1.w;
    for (int off = 8; off; off >>= 1) sq += __shfl_xor(sq, off);
    float inv = 1.0f / sqrtf(sq * (1.0f / 128.0f) + 1e-5f);
    float4 v0, v1;
    v0.x = d0.x*inv*g40.x + be0.x; v0.y = d0.y*inv*g40.y + be0.y;
    v0.z = d0.z*inv*g40.z + be0.z; v0.w = d0.w*inv*g40.w + be0.w;
    v1.x = d1.x*inv*g41.x + be1.x; v1.y = d1.y*inv*g41.y + be1.y;
    v1.z = d1.z*inv*g41.z + be1.z; v1.w = d1.w*inv*g41.w + be1.w;
    const int si = s_src[row];
    float* dst = (row < 16) ? out0 + ((size_t)b * NA + si) * Dd
                            : out1 + ((size_t)b * NL + si) * Dd;
    *(float4*)(dst + 4 * c) = v0;
    *(float4*)(dst + 64 + 4 * c) = v1;
  }
}

// ---------------------------------------------------------------------------
extern "C" void kernel_launch(void* const* d_in, const int* in_sizes, int n_in,
                              void* d_out, int out_size, void* d_ws, size_t ws_size,
                              hipStream_t stream) {
  const float* actor_feat = (const float*)d_in[0];
  const float* lane_feat  = (const float*)d_in[1];
  const float* lc         = (const float*)d_in[2];
  const float* xc         = (const float*)d_in[3];
  const float* spike      = (const float*)d_in[4];
  const unsigned char* avalid = (const unsigned char*)d_in[5];
  const unsigned char* lvalid = (const unsigned char*)d_in[6];
  const float* W0a = (const float*)d_in[7];
  const float* b0a = (const float*)d_in[8];
  const float* W0b = (const float*)d_in[9];
  const float* b0b = (const float*)d_in[10];
  const float* W1a = (const float*)d_in[11];
  const float* b1a = (const float*)d_in[12];
  const float* W1b = (const float*)d_in[13];
  const float* b1b = (const float*)d_in[14];
  const float* gamma = (const float*)d_in[15];
  const float* beta  = (const float*)d_in[16];

  int* aidx = (int*)d_ws;
  int* lidx = aidx + Bsz * KA;

  float* out0 = (float*)d_out;
  float* out1 = out0 + (size_t)Bsz * NA * Dd;

  idx_kernel<<<Bsz, 256, 0, stream>>>(spike, avalid, xc, lc, lvalid, aidx, lidx);
  hipMemcpyAsync(out0, actor_feat, (size_t)Bsz * NA * Dd * sizeof(float),
                 hipMemcpyDeviceToDevice, stream);
  hipMemcpyAsync(out1, lane_feat, (size_t)Bsz * NL * Dd * sizeof(float),
                 hipMemcpyDeviceToDevice, stream);
  mlp3_kernel<<<Bsz, 64, 0, stream>>>(
      actor_feat, lane_feat, aidx, lidx,
      W0a, b0a, W0b, b0b, W1a, b1a, W1b, b1b, gamma, beta, out0, out1);
}

// Round 10
// 172.817 us; speedup vs baseline: 1.7209x; 1.7209x over previous
//
#include <hip/hip_runtime.h>
#include <math.h>

#define Bsz 512
#define NA  128
#define NL  512
#define Dd  128
#define KA  16
#define KL  16

// ---------------------------------------------------------------------------
// Kernel A: per-batch index selection (one block per batch) — proven R5-R7.
// ---------------------------------------------------------------------------
__global__ __launch_bounds__(256) void idx_kernel(
    const float* __restrict__ spike, const unsigned char* __restrict__ avalid,
    const float* __restrict__ xc, const float* __restrict__ lc,
    const unsigned char* __restrict__ lvalid,
    int* __restrict__ aidx, int* __restrict__ lidx) {
  const int b = blockIdx.x;
  const int tid = threadIdx.x;

  __shared__ float s_ax[KA], s_ay[KA];
  __shared__ int   s_ai[KA];
  __shared__ float s_ld[NL];
  __shared__ float s_rv[4];
  __shared__ int   s_ri[4];
  __shared__ int   s_flag;

  if (tid == 0) s_flag = 0;
  __syncthreads();
  {
    int any = 0;
    for (int i = tid; i < 4096; i += 256)
      if ((i & 3) && avalid[i]) any = 1;
    if (any) atomicOr(&s_flag, 1);
  }
  __syncthreads();
  const int isbyte = s_flag;

#define VALID_AT(P, I) (isbyte ? (int)(P)[I] : ((const int*)(P))[I])

  if (tid < 64) {
    float v0 = VALID_AT(avalid, b * NA + tid)      ? spike[b * NA + tid]      : -INFINITY;
    float v1 = VALID_AT(avalid, b * NA + tid + 64) ? spike[b * NA + tid + 64] : -INFINITY;
    for (int it = 0; it < KA; ++it) {
      float bv = v0; int bi = tid;
      if (v1 > bv) { bv = v1; bi = tid + 64; }
      for (int off = 32; off; off >>= 1) {
        float ov = __shfl_xor(bv, off);
        int   oi = __shfl_xor(bi, off);
        if (ov > bv || (ov == bv && oi < bi)) { bv = ov; bi = oi; }
      }
      if (bi == tid)      v0 = -INFINITY;
      if (bi == tid + 64) v1 = -INFINITY;
      if (tid == 0) s_ai[it] = bi;
    }
  }
  __syncthreads();
  if (tid < KA) {
    int a = s_ai[tid];
    aidx[b * KA + tid] = a;
    s_ax[tid] = xc[(b * NA + a) * 2 + 0];
    s_ay[tid] = xc[(b * NA + a) * 2 + 1];
  }
  __syncthreads();

  for (int l = tid; l < NL; l += 256) {
    float lx = lc[(b * NL + l) * 2 + 0];
    float ly = lc[(b * NL + l) * 2 + 1];
    float best = INFINITY;
#pragma unroll
    for (int a = 0; a < KA; ++a) {
      float dx = s_ax[a] - lx, dy = s_ay[a] - ly;
      float d2 = __fadd_rn(__fmul_rn(dx, dx), __fmul_rn(dy, dy));
      best = fminf(best, d2);
    }
    best = sqrtf(best);
    s_ld[l] = VALID_AT(lvalid, b * NL + l) ? best : INFINITY;
  }
  __syncthreads();

  const int wid = tid >> 6, lane = tid & 63;
  for (int it = 0; it < KL; ++it) {
    float bv = s_ld[tid]; int bi = tid;
    float v2 = s_ld[tid + 256];
    if (v2 < bv) { bv = v2; bi = tid + 256; }
    for (int off = 32; off; off >>= 1) {
      float ov = __shfl_xor(bv, off);
      int   oi = __shfl_xor(bi, off);
      if (ov < bv || (ov == bv && oi < bi)) { bv = ov; bi = oi; }
    }
    if (lane == 0) { s_rv[wid] = bv; s_ri[wid] = bi; }
    __syncthreads();
    if (tid == 0) {
      float fbv = s_rv[0]; int fbi = s_ri[0];
      for (int w = 1; w < 4; ++w)
        if (s_rv[w] < fbv || (s_rv[w] == fbv && s_ri[w] < fbi)) { fbv = s_rv[w]; fbi = s_ri[w]; }
      lidx[b * KL + it] = fbi;
      s_ld[fbi] = INFINITY;
    }
    __syncthreads();
  }
#undef VALID_AT
}

// ---------------------------------------------------------------------------
// Kernel B (mlp4): 4 independent waves per block, each wave = 8 rows of one
// batch (barrier-free — matvec/GELU/LN are all row-local). Lane (r=l>>4,
// c=l&15) owns rows {r, r+4} (local) and cols {4c..4c+3, 64+4c..4c+67}.
// Weights read straight from global (L2-hot; 16 unique addrs/instr -> one
// 256B fetch), 2-deep register double-buffer prefetched under the FMAs.
// LDS holds only x/u (per-wave 8x132 slice; x-reads are 4-addr broadcasts).
// ---------------------------------------------------------------------------

__device__ __forceinline__ float gelu1(float t) {
  return 0.5f * t * (1.0f + erff(t * 0.70710678118654752f));
}

#define FMA4(A, S, W)                                                 \
  A.x = fmaf((S), (W).x, A.x); A.y = fmaf((S), (W).y, A.y);           \
  A.z = fmaf((S), (W).z, A.z); A.w = fmaf((S), (W).w, A.w);

// load chunk CH (4 k-rows) of W into regs P0..P7 (P0-3 lo cols, P4-7 hi)
#define WLOAD8(P, CH)                                                 \
  P##0 = *(const float4*)(Wp + ((CH)*4+0)*128 + 4*c);                 \
  P##1 = *(const float4*)(Wp + ((CH)*4+1)*128 + 4*c);                 \
  P##2 = *(const float4*)(Wp + ((CH)*4+2)*128 + 4*c);                 \
  P##3 = *(const float4*)(Wp + ((CH)*4+3)*128 + 4*c);                 \
  P##4 = *(const float4*)(Wp + ((CH)*4+0)*128 + 64 + 4*c);            \
  P##5 = *(const float4*)(Wp + ((CH)*4+1)*128 + 64 + 4*c);            \
  P##6 = *(const float4*)(Wp + ((CH)*4+2)*128 + 64 + 4*c);            \
  P##7 = *(const float4*)(Wp + ((CH)*4+3)*128 + 64 + 4*c);

#define FMACHUNK(CH, P)                                               \
  { float4 x0 = *(const float4*)&sx[row0 * 132 + (CH)*4];             \
    float4 x1 = *(const float4*)&sx[row1 * 132 + (CH)*4];             \
    FMA4(a00, x0.x, P##0) FMA4(a01, x0.x, P##4)                       \
    FMA4(a00, x0.y, P##1) FMA4(a01, x0.y, P##5)                       \
    FMA4(a00, x0.z, P##2) FMA4(a01, x0.z, P##6)                       \
    FMA4(a00, x0.w, P##3) FMA4(a01, x0.w, P##7)                       \
    FMA4(a10, x1.x, P##0) FMA4(a11, x1.x, P##4)                       \
    FMA4(a10, x1.y, P##1) FMA4(a11, x1.y, P##5)                       \
    FMA4(a10, x1.z, P##2) FMA4(a11, x1.z, P##6)                       \
    FMA4(a10, x1.w, P##3) FMA4(a11, x1.w, P##7) }

#define MATVEC4(WPTR, BPTR)                                           \
  { const float* Wp = (WPTR);                                         \
    { float4 bA = *(const float4*)((BPTR) + 4*c);                     \
      float4 bB = *(const float4*)((BPTR) + 64 + 4*c);                \
      a00 = bA; a01 = bB; a10 = bA; a11 = bB; }                       \
    float4 pA0,pA1,pA2,pA3,pA4,pA5,pA6,pA7;                           \
    float4 pB0,pB1,pB2,pB3,pB4,pB5,pB6,pB7;                           \
    WLOAD8(pA, 0)                                                     \
    _Pragma("unroll 1")                                               \
    for (int t = 0; t < 16; ++t) {                                    \
      const int ch0 = 2*t;                                            \
      WLOAD8(pB, ch0 + 1)                                             \
      FMACHUNK(ch0, pA)                                               \
      WLOAD8(pA, (ch0 + 2) & 31)                                      \
      FMACHUNK(ch0 + 1, pB)                                           \
    }                                                                 \
  }

// LN over one row (16 lanes x 8 cols): h quads -> v quads
#define LNROW(HA, HB, VA, VB)                                         \
  { float s = HA.x+HA.y+HA.z+HA.w + HB.x+HB.y+HB.z+HB.w;              \
    s += __shfl_xor(s, 1); s += __shfl_xor(s, 2);                     \
    s += __shfl_xor(s, 4); s += __shfl_xor(s, 8);                     \
    float mean = s * (1.0f / 128.0f);                                 \
    float4 dA, dB;                                                    \
    dA.x = HA.x-mean; dA.y = HA.y-mean; dA.z = HA.z-mean; dA.w = HA.w-mean; \
    dB.x = HB.x-mean; dB.y = HB.y-mean; dB.z = HB.z-mean; dB.w = HB.w-mean; \
    float ss = dA.x*dA.x+dA.y*dA.y+dA.z*dA.z+dA.w*dA.w                \
             + dB.x*dB.x+dB.y*dB.y+dB.z*dB.z+dB.w*dB.w;               \
    ss += __shfl_xor(ss, 1); ss += __shfl_xor(ss, 2);                 \
    ss += __shfl_xor(ss, 4); ss += __shfl_xor(ss, 8);                 \
    float inv = 1.0f / sqrtf(ss * (1.0f / 128.0f) + 1e-5f);           \
    VA.x = dA.x*inv*gmA.x + beA.x; VA.y = dA.y*inv*gmA.y + beA.y;     \
    VA.z = dA.z*inv*gmA.z + beA.z; VA.w = dA.w*inv*gmA.w + beA.w;     \
    VB.x = dB.x*inv*gmB.x + beB.x; VB.y = dB.y*inv*gmB.y + beB.y;     \
    VB.z = dB.z*inv*gmB.z + beB.z; VB.w = dB.w*inv*gmB.w + beB.w; }

__global__ __launch_bounds__(256, 2) void mlp4_kernel(
    const float* __restrict__ actor_feat, const float* __restrict__ lane_feat,
    const int* __restrict__ aidx, const int* __restrict__ lidx,
    const float* __restrict__ W0a, const float* __restrict__ b0a,
    const float* __restrict__ W0b, const float* __restrict__ b0b,
    const float* __restrict__ W1a, const float* __restrict__ b1a,
    const float* __restrict__ W1b, const float* __restrict__ b1b,
    const float* __restrict__ gamma, const float* __restrict__ beta,
    float* __restrict__ out0, float* __restrict__ out1) {
  __shared__ float s_x[4 * 8 * 132];   // 4 independent per-wave 8x132 slices

  const int tid = threadIdx.x;
  const int b = blockIdx.x;
  const int q = tid >> 6;              // wave = quarter of the batch
  const int l = tid & 63;
  const int r = l >> 4, c = l & 15;

  float* sx = s_x + q * 8 * 132;

  // ---- gather this wave's 8 rows (8 lanes per row, coalesced float4) ----
  {
    const int lr = l >> 3, c8 = l & 7;
    const int gr = q * 8 + lr;
    const int src = (gr < 16) ? aidx[b * KA + gr] : lidx[b * KL + gr - 16];
    const float* srow = (gr < 16)
        ? actor_feat + ((size_t)b * NA + src) * Dd
        : lane_feat  + ((size_t)b * NL + src) * Dd;
#pragma unroll
    for (int tq = 0; tq < 4; ++tq)
      *(float4*)&sx[lr * 132 + 4 * (c8 + 8 * tq)] =
          *(const float4*)(srow + 4 * (c8 + 8 * tq));
  }

  const int row0 = r, row1 = r + 4;    // local rows in sx

  const float4 gmA = *(const float4*)(gamma + 4 * c);
  const float4 gmB = *(const float4*)(gamma + 64 + 4 * c);
  const float4 beA = *(const float4*)(beta + 4 * c);
  const float4 beB = *(const float4*)(beta + 64 + 4 * c);

  // residual regs (lane's own slice of x; same-wave LDS ordering)
  float4 res00 = *(const float4*)&sx[row0 * 132 + 4 * c];
  float4 res01 = *(const float4*)&sx[row0 * 132 + 64 + 4 * c];
  float4 res10 = *(const float4*)&sx[row1 * 132 + 4 * c];
  float4 res11 = *(const float4*)&sx[row1 * 132 + 64 + 4 * c];

  float4 a00, a01, a10, a11;

  // ================= layer 0 =================
  MATVEC4(W0a, b0a);
  {  // GELU -> sx (all lanes past their reads of x by SIMT program order)
    float4 u;
    u.x=gelu1(a00.x); u.y=gelu1(a00.y); u.z=gelu1(a00.z); u.w=gelu1(a00.w);
    *(float4*)&sx[row0 * 132 + 4 * c] = u;
    u.x=gelu1(a01.x); u.y=gelu1(a01.y); u.z=gelu1(a01.z); u.w=gelu1(a01.w);
    *(float4*)&sx[row0 * 132 + 64 + 4 * c] = u;
    u.x=gelu1(a10.x); u.y=gelu1(a10.y); u.z=gelu1(a10.z); u.w=gelu1(a10.w);
    *(float4*)&sx[row1 * 132 + 4 * c] = u;
    u.x=gelu1(a11.x); u.y=gelu1(a11.y); u.z=gelu1(a11.z); u.w=gelu1(a11.w);
    *(float4*)&sx[row1 * 132 + 64 + 4 * c] = u;
  }

  MATVEC4(W0b, b0b);
  {  // residual + LN -> sx (layer-1 input), update residual regs
    float4 h00, h01, h10, h11, v00, v01, v10, v11;
    h00.x=res00.x+a00.x; h00.y=res00.y+a00.y; h00.z=res00.z+a00.z; h00.w=res00.w+a00.w;
    h01.x=res01.x+a01.x; h01.y=res01.y+a01.y; h01.z=res01.z+a01.z; h01.w=res01.w+a01.w;
    h10.x=res10.x+a10.x; h10.y=res10.y+a10.y; h10.z=res10.z+a10.z; h10.w=res10.w+a10.w;
    h11.x=res11.x+a11.x; h11.y=res11.y+a11.y; h11.z=res11.z+a11.z; h11.w=res11.w+a11.w;
    LNROW(h00, h01, v00, v01)
    LNROW(h10, h11, v10, v11)
    *(float4*)&sx[row0 * 132 + 4 * c] = v00;
    *(float4*)&sx[row0 * 132 + 64 + 4 * c] = v01;
    *(float4*)&sx[row1 * 132 + 4 * c] = v10;
    *(float4*)&sx[row1 * 132 + 64 + 4 * c] = v11;
    res00 = v00; res01 = v01; res10 = v10; res11 = v11;
  }

  // ================= layer 1 =================
  MATVEC4(W1a, b1a);
  {
    float4 u;
    u.x=gelu1(a00.x); u.y=gelu1(a00.y); u.z=gelu1(a00.z); u.w=gelu1(a00.w);
    *(float4*)&sx[row0 * 132 + 4 * c] = u;
    u.x=gelu1(a01.x); u.y=gelu1(a01.y); u.z=gelu1(a01.z); u.w=gelu1(a01.w);
    *(float4*)&sx[row0 * 132 + 64 + 4 * c] = u;
    u.x=gelu1(a10.x); u.y=gelu1(a10.y); u.z=gelu1(a10.z); u.w=gelu1(a10.w);
    *(float4*)&sx[row1 * 132 + 4 * c] = u;
    u.x=gelu1(a11.x); u.y=gelu1(a11.y); u.z=gelu1(a11.z); u.w=gelu1(a11.w);
    *(float4*)&sx[row1 * 132 + 64 + 4 * c] = u;
  }

  MATVEC4(W1b, b1b);
  {  // residual + LN -> scatter to global
    float4 h00, h01, h10, h11, v00, v01, v10, v11;
    h00.x=res00.x+a00.x; h00.y=res00.y+a00.y; h00.z=res00.z+a00.z; h00.w=res00.w+a00.w;
    h01.x=res01.x+a01.x; h01.y=res01.y+a01.y; h01.z=res01.z+a01.z; h01.w=res01.w+a01.w;
    h10.x=res10.x+a10.x; h10.y=res10.y+a10.y; h10.z=res10.z+a10.z; h10.w=res10.w+a10.w;
    h11.x=res11.x+a11.x; h11.y=res11.y+a11.y; h11.z=res11.z+a11.z; h11.w=res11.w+a11.w;
    LNROW(h00, h01, v00, v01)
    LNROW(h10, h11, v10, v11)
    const int gr0 = q * 8 + row0, gr1 = q * 8 + row1;
    const int s0 = (gr0 < 16) ? aidx[b * KA + gr0] : lidx[b * KL + gr0 - 16];
    const int s1 = (gr1 < 16) ? aidx[b * KA + gr1] : lidx[b * KL + gr1 - 16];
    float* d0 = (gr0 < 16) ? out0 + ((size_t)b * NA + s0) * Dd
                           : out1 + ((size_t)b * NL + s0) * Dd;
    float* d1 = (gr1 < 16) ? out0 + ((size_t)b * NA + s1) * Dd
                           : out1 + ((size_t)b * NL + s1) * Dd;
    *(float4*)(d0 + 4 * c) = v00;
    *(float4*)(d0 + 64 + 4 * c) = v01;
    *(float4*)(d1 + 4 * c) = v10;
    *(float4*)(d1 + 64 + 4 * c) = v11;
  }
}

// ---------------------------------------------------------------------------
extern "C" void kernel_launch(void* const* d_in, const int* in_sizes, int n_in,
                              void* d_out, int out_size, void* d_ws, size_t ws_size,
                              hipStream_t stream) {
  const float* actor_feat = (const float*)d_in[0];
  const float* lane_feat  = (const float*)d_in[1];
  const float* lc         = (const float*)d_in[2];
  const float* xc         = (const float*)d_in[3];
  const float* spike      = (const float*)d_in[4];
  const unsigned char* avalid = (const unsigned char*)d_in[5];
  const unsigned char* lvalid = (const unsigned char*)d_in[6];
  const float* W0a = (const float*)d_in[7];
  const float* b0a = (const float*)d_in[8];
  const float* W0b = (const float*)d_in[9];
  const float* b0b = (const float*)d_in[10];
  const float* W1a = (const float*)d_in[11];
  const float* b1a = (const float*)d_in[12];
  const float* W1b = (const float*)d_in[13];
  const float* b1b = (const float*)d_in[14];
  const float* gamma = (const float*)d_in[15];
  const float* beta  = (const float*)d_in[16];

  int* aidx = (int*)d_ws;
  int* lidx = aidx + Bsz * KA;

  float* out0 = (float*)d_out;
  float* out1 = out0 + (size_t)Bsz * NA * Dd;

  idx_kernel<<<Bsz, 256, 0, stream>>>(spike, avalid, xc, lc, lvalid, aidx, lidx);
  hipMemcpyAsync(out0, actor_feat, (size_t)Bsz * NA * Dd * sizeof(float),
                 hipMemcpyDeviceToDevice, stream);
  hipMemcpyAsync(out1, lane_feat, (size_t)Bsz * NL * Dd * sizeof(float),
                 hipMemcpyDeviceToDevice, stream);
  mlp4_kernel<<<Bsz, 256, 0, stream>>>(
      actor_feat, lane_feat, aidx, lidx,
      W0a, b0a, W0b, b0b, W1a, b1a, W1b, b1b, gamma, beta, out0, out1);
}

// Round 12
// 170.934 us; speedup vs baseline: 1.7399x; 1.0110x over previous
//
#include <hip/hip_runtime.h>
#include <math.h>

#define Bsz 512
#define NA  128
#define NL  512
#define Dd  128
#define KA  16
#define KL  16

// ---------------------------------------------------------------------------
// Kernel A: per-batch index selection (one block per batch) — proven R5-R10.
// ---------------------------------------------------------------------------
__global__ __launch_bounds__(256) void idx_kernel(
    const float* __restrict__ spike, const unsigned char* __restrict__ avalid,
    const float* __restrict__ xc, const float* __restrict__ lc,
    const unsigned char* __restrict__ lvalid,
    int* __restrict__ aidx, int* __restrict__ lidx) {
  const int b = blockIdx.x;
  const int tid = threadIdx.x;

  __shared__ float s_ax[KA], s_ay[KA];
  __shared__ int   s_ai[KA];
  __shared__ float s_ld[NL];
  __shared__ float s_rv[4];
  __shared__ int   s_ri[4];
  __shared__ int   s_flag;

  if (tid == 0) s_flag = 0;
  __syncthreads();
  {
    int any = 0;
    for (int i = tid; i < 4096; i += 256)
      if ((i & 3) && avalid[i]) any = 1;
    if (any) atomicOr(&s_flag, 1);
  }
  __syncthreads();
  const int isbyte = s_flag;

#define VALID_AT(P, I) (isbyte ? (int)(P)[I] : ((const int*)(P))[I])

  if (tid < 64) {
    float v0 = VALID_AT(avalid, b * NA + tid)      ? spike[b * NA + tid]      : -INFINITY;
    float v1 = VALID_AT(avalid, b * NA + tid + 64) ? spike[b * NA + tid + 64] : -INFINITY;
    for (int it = 0; it < KA; ++it) {
      float bv = v0; int bi = tid;
      if (v1 > bv) { bv = v1; bi = tid + 64; }
      for (int off = 32; off; off >>= 1) {
        float ov = __shfl_xor(bv, off);
        int   oi = __shfl_xor(bi, off);
        if (ov > bv || (ov == bv && oi < bi)) { bv = ov; bi = oi; }
      }
      if (bi == tid)      v0 = -INFINITY;
      if (bi == tid + 64) v1 = -INFINITY;
      if (tid == 0) s_ai[it] = bi;
    }
  }
  __syncthreads();
  if (tid < KA) {
    int a = s_ai[tid];
    aidx[b * KA + tid] = a;
    s_ax[tid] = xc[(b * NA + a) * 2 + 0];
    s_ay[tid] = xc[(b * NA + a) * 2 + 1];
  }
  __syncthreads();

  for (int l = tid; l < NL; l += 256) {
    float lx = lc[(b * NL + l) * 2 + 0];
    float ly = lc[(b * NL + l) * 2 + 1];
    float best = INFINITY;
#pragma unroll
    for (int a = 0; a < KA; ++a) {
      float dx = s_ax[a] - lx, dy = s_ay[a] - ly;
      float d2 = __fadd_rn(__fmul_rn(dx, dx), __fmul_rn(dy, dy));
      best = fminf(best, d2);
    }
    best = sqrtf(best);
    s_ld[l] = VALID_AT(lvalid, b * NL + l) ? best : INFINITY;
  }
  __syncthreads();

  const int wid = tid >> 6, lane = tid & 63;
  for (int it = 0; it < KL; ++it) {
    float bv = s_ld[tid]; int bi = tid;
    float v2 = s_ld[tid + 256];
    if (v2 < bv) { bv = v2; bi = tid + 256; }
    for (int off = 32; off; off >>= 1) {
      float ov = __shfl_xor(bv, off);
      int   oi = __shfl_xor(bi, off);
      if (ov < bv || (ov == bv && oi < bi)) { bv = ov; bi = oi; }
    }
    if (lane == 0) { s_rv[wid] = bv; s_ri[wid] = bi; }
    __syncthreads();
    if (tid == 0) {
      float fbv = s_rv[0]; int fbi = s_ri[0];
      for (int w = 1; w < 4; ++w)
        if (s_rv[w] < fbv || (s_rv[w] == fbv && s_ri[w] < fbi)) { fbv = s_rv[w]; fbi = s_ri[w]; }
      lidx[b * KL + it] = fbi;
      s_ld[fbi] = INFINITY;
    }
    __syncthreads();
  }
#undef VALID_AT
}

// ---------------------------------------------------------------------------
// Kernel B (mlp5): mlp4 + sched_barrier-pinned software pipeline.
// 4 independent waves/block, 8 rows/wave, barrier-free. Weights from global
// (L2-hot) in a 2-deep REGISTER double-buffer; x in a 2-deep register buffer
// read from LDS. sched_barrier(0) fences stop hipcc sinking the loads into
// their use sites (R10: VGPR=64 proved the source-level pipeline collapsed).
// ---------------------------------------------------------------------------

__device__ __forceinline__ float gelu1(float t) {
  return 0.5f * t * (1.0f + erff(t * 0.70710678118654752f));
}

#define SBAR __builtin_amdgcn_sched_barrier(0)

#define FMA4(A, S, W)                                                 \
  A.x = fmaf((S), (W).x, A.x); A.y = fmaf((S), (W).y, A.y);           \
  A.z = fmaf((S), (W).z, A.z); A.w = fmaf((S), (W).w, A.w);

// load chunk CH (4 k-rows) of W into regs P0..P7 (P0-3 lo cols, P4-7 hi)
#define WLOAD8(P, CH)                                                 \
  P##0 = *(const float4*)(Wp + ((CH)*4+0)*128 + 4*c);                 \
  P##1 = *(const float4*)(Wp + ((CH)*4+1)*128 + 4*c);                 \
  P##2 = *(const float4*)(Wp + ((CH)*4+2)*128 + 4*c);                 \
  P##3 = *(const float4*)(Wp + ((CH)*4+3)*128 + 4*c);                 \
  P##4 = *(const float4*)(Wp + ((CH)*4+0)*128 + 64 + 4*c);            \
  P##5 = *(const float4*)(Wp + ((CH)*4+1)*128 + 64 + 4*c);            \
  P##6 = *(const float4*)(Wp + ((CH)*4+2)*128 + 64 + 4*c);            \
  P##7 = *(const float4*)(Wp + ((CH)*4+3)*128 + 64 + 4*c);

// x double-buffer load (2 ds_read_b128); pasted token followed by '=' (safe)
#define XLOAD(X, CH)                                                  \
  X##0 = *(const float4*)&sx[row0 * 132 + (CH)*4];                    \
  X##1 = *(const float4*)&sx[row1 * 132 + (CH)*4];

// pure-register FMA block: 64 fmaf. X0/X1 passed explicitly — NO token
// pasting adjacent to member access (pp-number '0.x' gotcha from R11).
#define FMACHUNK(P, X0, X1)                                           \
  { FMA4(a00, (X0).x, P##0) FMA4(a01, (X0).x, P##4)                   \
    FMA4(a00, (X0).y, P##1) FMA4(a01, (X0).y, P##5)                   \
    FMA4(a00, (X0).z, P##2) FMA4(a01, (X0).z, P##6)                   \
    FMA4(a00, (X0).w, P##3) FMA4(a01, (X0).w, P##7)                   \
    FMA4(a10, (X1).x, P##0) FMA4(a11, (X1).x, P##4)                   \
    FMA4(a10, (X1).y, P##1) FMA4(a11, (X1).y, P##5)                   \
    FMA4(a10, (X1).z, P##2) FMA4(a11, (X1).z, P##6)                   \
    FMA4(a10, (X1).w, P##3) FMA4(a11, (X1).w, P##7) }

#define MATVEC5(WPTR, BPTR)                                           \
  { const float* Wp = (WPTR);                                         \
    { float4 bA = *(const float4*)((BPTR) + 4*c);                     \
      float4 bB = *(const float4*)((BPTR) + 64 + 4*c);                \
      a00 = bA; a01 = bB; a10 = bA; a11 = bB; }                       \
    float4 pA0,pA1,pA2,pA3,pA4,pA5,pA6,pA7;                           \
    float4 pB0,pB1,pB2,pB3,pB4,pB5,pB6,pB7;                           \
    float4 xA0, xA1, xB0, xB1;                                        \
    WLOAD8(pA, 0) XLOAD(xA, 0)                                        \
    SBAR;                                                             \
    _Pragma("unroll 1")                                               \
    for (int t = 0; t < 16; ++t) {                                    \
      const int ch0 = 2*t;                                            \
      WLOAD8(pB, ch0 + 1) XLOAD(xB, ch0 + 1)                          \
      SBAR;                                                           \
      FMACHUNK(pA, xA0, xA1)                                          \
      SBAR;                                                           \
      WLOAD8(pA, (ch0 + 2) & 31) XLOAD(xA, (ch0 + 2) & 31)            \
      SBAR;                                                           \
      FMACHUNK(pB, xB0, xB1)                                          \
      SBAR;                                                           \
    }                                                                 \
  }

// LN over one row (16 lanes x 8 cols): h quads -> v quads
#define LNROW(HA, HB, VA, VB)                                         \
  { float s = HA.x+HA.y+HA.z+HA.w + HB.x+HB.y+HB.z+HB.w;              \
    s += __shfl_xor(s, 1); s += __shfl_xor(s, 2);                     \
    s += __shfl_xor(s, 4); s += __shfl_xor(s, 8);                     \
    float mean = s * (1.0f / 128.0f);                                 \
    float4 dA, dB;                                                    \
    dA.x = HA.x-mean; dA.y = HA.y-mean; dA.z = HA.z-mean; dA.w = HA.w-mean; \
    dB.x = HB.x-mean; dB.y = HB.y-mean; dB.z = HB.z-mean; dB.w = HB.w-mean; \
    float ss = dA.x*dA.x+dA.y*dA.y+dA.z*dA.z+dA.w*dA.w                \
             + dB.x*dB.x+dB.y*dB.y+dB.z*dB.z+dB.w*dB.w;               \
    ss += __shfl_xor(ss, 1); ss += __shfl_xor(ss, 2);                 \
    ss += __shfl_xor(ss, 4); ss += __shfl_xor(ss, 8);                 \
    float inv = 1.0f / sqrtf(ss * (1.0f / 128.0f) + 1e-5f);           \
    VA.x = dA.x*inv*gmA.x + beA.x; VA.y = dA.y*inv*gmA.y + beA.y;     \
    VA.z = dA.z*inv*gmA.z + beA.z; VA.w = dA.w*inv*gmA.w + beA.w;     \
    VB.x = dB.x*inv*gmB.x + beB.x; VB.y = dB.y*inv*gmB.y + beB.y;     \
    VB.z = dB.z*inv*gmB.z + beB.z; VB.w = dB.w*inv*gmB.w + beB.w; }

__global__ __launch_bounds__(256, 2) void mlp5_kernel(
    const float* __restrict__ actor_feat, const float* __restrict__ lane_feat,
    const int* __restrict__ aidx, const int* __restrict__ lidx,
    const float* __restrict__ W0a, const float* __restrict__ b0a,
    const float* __restrict__ W0b, const float* __restrict__ b0b,
    const float* __restrict__ W1a, const float* __restrict__ b1a,
    const float* __restrict__ W1b, const float* __restrict__ b1b,
    const float* __restrict__ gamma, const float* __restrict__ beta,
    float* __restrict__ out0, float* __restrict__ out1) {
  __shared__ float s_x[4 * 8 * 132];   // 4 independent per-wave 8x132 slices

  const int tid = threadIdx.x;
  const int b = blockIdx.x;
  const int q = tid >> 6;              // wave = quarter of the batch
  const int l = tid & 63;
  const int r = l >> 4, c = l & 15;

  float* sx = s_x + q * 8 * 132;

  // ---- gather this wave's 8 rows (8 lanes per row, coalesced float4) ----
  {
    const int lr = l >> 3, c8 = l & 7;
    const int gr = q * 8 + lr;
    const int src = (gr < 16) ? aidx[b * KA + gr] : lidx[b * KL + gr - 16];
    const float* srow = (gr < 16)
        ? actor_feat + ((size_t)b * NA + src) * Dd
        : lane_feat  + ((size_t)b * NL + src) * Dd;
#pragma unroll
    for (int tq = 0; tq < 4; ++tq)
      *(float4*)&sx[lr * 132 + 4 * (c8 + 8 * tq)] =
          *(const float4*)(srow + 4 * (c8 + 8 * tq));
  }

  const int row0 = r, row1 = r + 4;    // local rows in sx

  const float4 gmA = *(const float4*)(gamma + 4 * c);
  const float4 gmB = *(const float4*)(gamma + 64 + 4 * c);
  const float4 beA = *(const float4*)(beta + 4 * c);
  const float4 beB = *(const float4*)(beta + 64 + 4 * c);

  // residual regs (lane's own slice of x; same-wave LDS ordering)
  float4 res00 = *(const float4*)&sx[row0 * 132 + 4 * c];
  float4 res01 = *(const float4*)&sx[row0 * 132 + 64 + 4 * c];
  float4 res10 = *(const float4*)&sx[row1 * 132 + 4 * c];
  float4 res11 = *(const float4*)&sx[row1 * 132 + 64 + 4 * c];

  float4 a00, a01, a10, a11;

  // ================= layer 0 =================
  MATVEC5(W0a, b0a);
  {  // GELU -> sx
    float4 u;
    u.x=gelu1(a00.x); u.y=gelu1(a00.y); u.z=gelu1(a00.z); u.w=gelu1(a00.w);
    *(float4*)&sx[row0 * 132 + 4 * c] = u;
    u.x=gelu1(a01.x); u.y=gelu1(a01.y); u.z=gelu1(a01.z); u.w=gelu1(a01.w);
    *(float4*)&sx[row0 * 132 + 64 + 4 * c] = u;
    u.x=gelu1(a10.x); u.y=gelu1(a10.y); u.z=gelu1(a10.z); u.w=gelu1(a10.w);
    *(float4*)&sx[row1 * 132 + 4 * c] = u;
    u.x=gelu1(a11.x); u.y=gelu1(a11.y); u.z=gelu1(a11.z); u.w=gelu1(a11.w);
    *(float4*)&sx[row1 * 132 + 64 + 4 * c] = u;
  }

  MATVEC5(W0b, b0b);
  {  // residual + LN -> sx (layer-1 input), update residual regs
    float4 h00, h01, h10, h11, v00, v01, v10, v11;
    h00.x=res00.x+a00.x; h00.y=res00.y+a00.y; h00.z=res00.z+a00.z; h00.w=res00.w+a00.w;
    h01.x=res01.x+a01.x; h01.y=res01.y+a01.y; h01.z=res01.z+a01.z; h01.w=res01.w+a01.w;
    h10.x=res10.x+a10.x; h10.y=res10.y+a10.y; h10.z=res10.z+a10.z; h10.w=res10.w+a10.w;
    h11.x=res11.x+a11.x; h11.y=res11.y+a11.y; h11.z=res11.z+a11.z; h11.w=res11.w+a11.w;
    LNROW(h00, h01, v00, v01)
    LNROW(h10, h11, v10, v11)
    *(float4*)&sx[row0 * 132 + 4 * c] = v00;
    *(float4*)&sx[row0 * 132 + 64 + 4 * c] = v01;
    *(float4*)&sx[row1 * 132 + 4 * c] = v10;
    *(float4*)&sx[row1 * 132 + 64 + 4 * c] = v11;
    res00 = v00; res01 = v01; res10 = v10; res11 = v11;
  }

  // ================= layer 1 =================
  MATVEC5(W1a, b1a);
  {
    float4 u;
    u.x=gelu1(a00.x); u.y=gelu1(a00.y); u.z=gelu1(a00.z); u.w=gelu1(a00.w);
    *(float4*)&sx[row0 * 132 + 4 * c] = u;
    u.x=gelu1(a01.x); u.y=gelu1(a01.y); u.z=gelu1(a01.z); u.w=gelu1(a01.w);
    *(float4*)&sx[row0 * 132 + 64 + 4 * c] = u;
    u.x=gelu1(a10.x); u.y=gelu1(a10.y); u.z=gelu1(a10.z); u.w=gelu1(a10.w);
    *(float4*)&sx[row1 * 132 + 4 * c] = u;
    u.x=gelu1(a11.x); u.y=gelu1(a11.y); u.z=gelu1(a11.z); u.w=gelu1(a11.w);
    *(float4*)&sx[row1 * 132 + 64 + 4 * c] = u;
  }

  MATVEC5(W1b, b1b);
  {  // residual + LN -> scatter to global
    float4 h00, h01, h10, h11, v00, v01, v10, v11;
    h00.x=res00.x+a00.x; h00.y=res00.y+a00.y; h00.z=res00.z+a00.z; h00.w=res00.w+a00.w;
    h01.x=res01.x+a01.x; h01.y=res01.y+a01.y; h01.z=res01.z+a01.z; h01.w=res01.w+a01.w;
    h10.x=res10.x+a10.x; h10.y=res10.y+a10.y; h10.z=res10.z+a10.z; h10.w=res10.w+a10.w;
    h11.x=res11.x+a11.x; h11.y=res11.y+a11.y; h11.z=res11.z+a11.z; h11.w=res11.w+a11.w;
    LNROW(h00, h01, v00, v01)
    LNROW(h10, h11, v10, v11)
    const int gr0 = q * 8 + row0, gr1 = q * 8 + row1;
    const int s0 = (gr0 < 16) ? aidx[b * KA + gr0] : lidx[b * KL + gr0 - 16];
    const int s1 = (gr1 < 16) ? aidx[b * KA + gr1] : lidx[b * KL + gr1 - 16];
    float* d0 = (gr0 < 16) ? out0 + ((size_t)b * NA + s0) * Dd
                           : out1 + ((size_t)b * NL + s0) * Dd;
    float* d1 = (gr1 < 16) ? out0 + ((size_t)b * NA + s1) * Dd
                           : out1 + ((size_t)b * NL + s1) * Dd;
    *(float4*)(d0 + 4 * c) = v00;
    *(float4*)(d0 + 64 + 4 * c) = v01;
    *(float4*)(d1 + 4 * c) = v10;
    *(float4*)(d1 + 64 + 4 * c) = v11;
  }
}

// ---------------------------------------------------------------------------
extern "C" void kernel_launch(void* const* d_in, const int* in_sizes, int n_in,
                              void* d_out, int out_size, void* d_ws, size_t ws_size,
                              hipStream_t stream) {
  const float* actor_feat = (const float*)d_in[0];
  const float* lane_feat  = (const float*)d_in[1];
  const float* lc         = (const float*)d_in[2];
  const float* xc         = (const float*)d_in[3];
  const float* spike      = (const float*)d_in[4];
  const unsigned char* avalid = (const unsigned char*)d_in[5];
  const unsigned char* lvalid = (const unsigned char*)d_in[6];
  const float* W0a = (const float*)d_in[7];
  const float* b0a = (const float*)d_in[8];
  const float* W0b = (const float*)d_in[9];
  const float* b0b = (const float*)d_in[10];
  const float* W1a = (const float*)d_in[11];
  const float* b1a = (const float*)d_in[12];
  const float* W1b = (const float*)d_in[13];
  const float* b1b = (const float*)d_in[14];
  const float* gamma = (const float*)d_in[15];
  const float* beta  = (const float*)d_in[16];

  int* aidx = (int*)d_ws;
  int* lidx = aidx + Bsz * KA;

  float* out0 = (float*)d_out;
  float* out1 = out0 + (size_t)Bsz * NA * Dd;

  idx_kernel<<<Bsz, 256, 0, stream>>>(spike, avalid, xc, lc, lvalid, aidx, lidx);
  hipMemcpyAsync(out0, actor_feat, (size_t)Bsz * NA * Dd * sizeof(float),
                 hipMemcpyDeviceToDevice, stream);
  hipMemcpyAsync(out1, lane_feat, (size_t)Bsz * NL * Dd * sizeof(float),
                 hipMemcpyDeviceToDevice, stream);
  mlp5_kernel<<<Bsz, 256, 0, stream>>>(
      actor_feat, lane_feat, aidx, lidx,
      W0a, b0a, W0b, b0b, W1a, b1a, W1b, b1b, gamma, beta, out0, out1);
}